// Round 10
// baseline (393.625 us; speedup 1.0000x reference)
//
#include <hip/hip_runtime.h>
#include <math.h>

typedef short short8 __attribute__((ext_vector_type(8)));
typedef float f32x4 __attribute__((ext_vector_type(4)));
typedef unsigned long long u64;

#define LOG2E 1.4426950408889634f

__device__ __forceinline__ unsigned short f2bf_rne(float f) {
    unsigned u = __float_as_uint(f);
    unsigned r = (u + 0x7fff + ((u >> 16) & 1)) >> 16;
    return (unsigned short)r;
}
__device__ __forceinline__ float bf2f(unsigned short h) {
    return __uint_as_float(((unsigned)h) << 16);
}
__device__ __forceinline__ void load_lds16(const void* g, void* l) {
    __builtin_amdgcn_global_load_lds((const __attribute__((address_space(1))) void*)g,
                                     (__attribute__((address_space(3))) void*)l,
                                     16, 0, 0);
}
template<int N>
__device__ __forceinline__ void waitvm() {
    asm volatile("s_waitcnt vmcnt(%0)" :: "n"(N) : "memory");
}
// 8 fp32 -> 8 fp8 e4m3 (RNE, saturating), scaled
__device__ __forceinline__ u64 pack8_fp8(const float* v, float s) {
    int lo = 0, hi = 0;
    lo = __builtin_amdgcn_cvt_pk_fp8_f32(v[0] * s, v[1] * s, lo, false);
    lo = __builtin_amdgcn_cvt_pk_fp8_f32(v[2] * s, v[3] * s, lo, true);
    hi = __builtin_amdgcn_cvt_pk_fp8_f32(v[4] * s, v[5] * s, hi, false);
    hi = __builtin_amdgcn_cvt_pk_fp8_f32(v[6] * s, v[7] * s, hi, true);
    return (u64)(unsigned)lo | ((u64)(unsigned)hi << 32);
}

// ---------------- cvt hidden fp32 -> bf16 ----------------
__global__ void cvt_h(const float* __restrict__ in, unsigned short* __restrict__ out)
{
    const int i = blockIdx.x * 256 + threadIdx.x;   // one float4 quad each
    const float4 v = *(const float4*)(in + (size_t)i * 4);
    ushort4 h;
    h.x = f2bf_rne(v.x); h.y = f2bf_rne(v.y);
    h.z = f2bf_rne(v.z); h.w = f2bf_rne(v.w);
    *(ushort4*)(out + (size_t)i * 4) = h;
}

// ---------------- fused prep (weights->fp8 swizzle + biases) + projections ----------------
// Convert path: panel-based LDS transpose (r9) — both HBM streams contiguous.
struct ProjDesc {
    const float* B;            // fp32 P matrix [N][1024]
    unsigned short* Cbf;       // bf16 Y [1024][ldc]
    unsigned char* Cf8;        // fp8 Y, granule-tile layout, Kpad cols
    int ldc; int nreal; int N; int Kpad; int gy_begin;
};

__global__ __launch_bounds__(256) void prepproj(
    const unsigned short* __restrict__ A,   // h_bf [1024][1024]
    ProjDesc p0, ProjDesc p1, ProjDesc p2, ProjDesc p3,
    const float* __restrict__ W0, const float* __restrict__ cw,
    const float* __restrict__ W1, const float* __restrict__ W2,
    const float* __restrict__ W3,
    const float* __restrict__ b0, const float* __restrict__ cb,
    const float* __restrict__ b1, const float* __restrict__ b2,
    const float* __restrict__ b3,
    unsigned char* __restrict__ Wb0, unsigned char* __restrict__ Wb1,
    unsigned char* __restrict__ Wb2, unsigned char* __restrict__ Wb3,
    float* __restrict__ bp)
{
    __shared__ char smem[34816];

    const int tid = threadIdx.x;
    const int bx = blockIdx.x;

    if (bx >= 96) {
        // ---------- convert path: panel-based LDS transpose ----------
        u64* lds = (u64*)smem;                 // [32][130] u64 = 33280 B
        const int NP = 2596;
        const int nconv = gridDim.x - 96;
        for (int pn = bx - 96; pn < NP; pn += nconv) {
            __syncthreads();                   // LDS reuse across panels
            if (pn < 788) {
                // ---- W0 / W1: 128 rows x 256 cols, KG=32 ----
                const bool isW0 = (pn < 628);
                const int tile = isW0 ? (pn >> 2) : (pn - 628);
                const int c0 = isW0 ? (pn & 3) * 256 : 0;
                unsigned char* dstm = isW0 ? Wb0 : Wb1;
                const int tstride = isW0 ? 131072 : 32768;
#pragma unroll
                for (int rp = 0; rp < 8; ++rp) {
                    const int row = rp * 16 + (tid >> 4);
                    const int colf = (tid & 15) * 16;
                    const int row_g = tile * 128 + row;
                    const float* s = nullptr;
                    if (isW0) {
                        if (row_g < 20000)      s = W0 + (size_t)row_g * 1024 + c0 + colf;
                        else if (row_g < 20003) s = cw + (size_t)(row_g - 20000) * 1024 + c0 + colf;
                    } else {
                        if (row_g < 20000)      s = W1 + (size_t)row_g * 256 + colf;
                    }
                    float f[16];
                    if (s) {
#pragma unroll
                        for (int q = 0; q < 4; ++q) {
                            const float4 v = *(const float4*)(s + q * 4);
                            f[q * 4 + 0] = v.x; f[q * 4 + 1] = v.y;
                            f[q * 4 + 2] = v.z; f[q * 4 + 3] = v.w;
                        }
                    } else {
#pragma unroll
                        for (int q = 0; q < 16; ++q) f[q] = 0.f;
                    }
                    const int kg = (tid & 15) * 2;
                    lds[kg * 130 + row]       = pack8_fp8(f,     16.0f);
                    lds[(kg + 1) * 130 + row] = pack8_fp8(f + 8, 16.0f);
                }
                __syncthreads();
                u64* dst = (u64*)(dstm + (size_t)tile * tstride) + (size_t)(c0 >> 3) * 128;
#pragma unroll
                for (int i = 0; i < 16; ++i) {
                    const int lin = i * 256 + tid;
                    const int kg = lin >> 7, r = lin & 127;
                    dst[lin] = lds[kg * 130 + r];
                }
            } else if (pn < 2052) {
                // ---- W2: 128 rows x 64 cols, KG=8 ----
                const int tile = pn - 788;
#pragma unroll
                for (int rp = 0; rp < 2; ++rp) {
                    const int row = rp * 64 + (tid >> 2);
                    const int colf = (tid & 3) * 16;
                    const int row_g = tile * 128 + row;
                    const float* s = (row_g < 160000) ? W2 + (size_t)row_g * 64 + colf : nullptr;
                    float f[16];
                    if (s) {
#pragma unroll
                        for (int q = 0; q < 4; ++q) {
                            const float4 v = *(const float4*)(s + q * 4);
                            f[q * 4 + 0] = v.x; f[q * 4 + 1] = v.y;
                            f[q * 4 + 2] = v.z; f[q * 4 + 3] = v.w;
                        }
                    } else {
#pragma unroll
                        for (int q = 0; q < 16; ++q) f[q] = 0.f;
                    }
                    const int kg = (tid & 3) * 2;
                    lds[kg * 130 + row]       = pack8_fp8(f,     16.0f);
                    lds[(kg + 1) * 130 + row] = pack8_fp8(f + 8, 16.0f);
                }
                __syncthreads();
                u64* dst = (u64*)(Wb2 + (size_t)tile * 8192);
#pragma unroll
                for (int i = 0; i < 4; ++i) {
                    const int lin = i * 256 + tid;
                    const int kg = lin >> 7, r = lin & 127;
                    dst[lin] = lds[kg * 130 + r];
                }
            } else {
                // ---- W3: 128 rows x 16 real cols; out kg 0..7, kg>=2 zero ----
                const int tile = pn - 2052;
                if (tid < 128) {
                    const int row = tid;
                    const int row_g = tile * 128 + row;
                    const float* s = (row_g < 67735) ? W3 + (size_t)row_g * 16 : nullptr;
                    float f[16];
                    if (s) {
#pragma unroll
                        for (int q = 0; q < 4; ++q) {
                            const float4 v = *(const float4*)(s + q * 4);
                            f[q * 4 + 0] = v.x; f[q * 4 + 1] = v.y;
                            f[q * 4 + 2] = v.z; f[q * 4 + 3] = v.w;
                        }
                    } else {
#pragma unroll
                        for (int q = 0; q < 16; ++q) f[q] = 0.f;
                    }
                    lds[row]       = pack8_fp8(f,     16.0f);
                    lds[130 + row] = pack8_fp8(f + 8, 16.0f);
                }
                __syncthreads();
                u64* dst = (u64*)(Wb3 + (size_t)tile * 8192);
#pragma unroll
                for (int i = 0; i < 4; ++i) {
                    const int lin = i * 256 + tid;
                    const int kg = lin >> 7, r = lin & 127;
                    dst[lin] = (kg < 2) ? lds[kg * 130 + r] : 0ull;
                }
            }
        }

        // ---------- padded biases, pre-scaled by log2e; pad rows -> -1e30 ----------
        const unsigned BN = 68000u;   // float4 units
        const unsigned stride = (gridDim.x - 96) * 256u;
        for (unsigned u = (bx - 96) * 256u + tid; u < BN; u += stride) {
            const unsigned idx0 = u * 4u;
            float e[4];
#pragma unroll
            for (int j = 0; j < 4; ++j) {
                const unsigned idx = idx0 + j;
                float v;
                if (idx < 20096u) {
                    v = (idx < 20000u) ? b0[idx] * LOG2E
                      : (idx < 20003u) ? cb[idx - 20000u] * LOG2E : -1e30f;
                } else if (idx < 40576u) {
                    const unsigned i1 = idx - 20096u;
                    v = (i1 < 20000u) ? b1[i1] * LOG2E : -1e30f;
                } else if (idx < 202368u) {
                    const unsigned i2 = idx - 40576u;
                    v = (i2 < 160000u) ? b2[i2] * LOG2E : -1e30f;
                } else {
                    const unsigned i3 = idx - 202368u;
                    v = (i3 < 67735u) ? b3[i3] * LOG2E : -1e30f;
                }
                e[j] = v;
            }
            *(float4*)(bp + idx0) = make_float4(e[0], e[1], e[2], e[3]);
        }
        return;
    }

    // ---------- projection GEMM path ----------
    unsigned short* As = (unsigned short*)smem;            // [8192] bf16
    unsigned short* Bs = (unsigned short*)(smem + 16384);  // [8192] bf16

    const int mt = bx & 7;
    const int py = bx >> 3;
    ProjDesc p = (py >= p3.gy_begin) ? p3 : (py >= p2.gy_begin) ? p2
               : (py >= p1.gy_begin) ? p1 : p0;

    const int w = tid >> 6;
    const int l = tid & 63;
    const int m0 = mt * 128;
    const int n0 = (py - p.gy_begin) * 128;
    const int wm = (w >> 1) * 64;
    const int wn = (w & 1) * 64;
    const int lane16 = l & 15;
    const int quad = l >> 4;

    const unsigned short* aptr[4];
    int ag_base[4];
#pragma unroll
    for (int i = 0; i < 4; ++i) {
        const int g = w * 256 + i * 64 + l;
        aptr[i] = A + (size_t)(m0 + (g & 127)) * 1024 + (g >> 7) * 8;
        ag_base[i] = (w * 256 + i * 64) * 8;
    }

    const int bn = tid >> 1;
    const int bhalf = tid & 1;
    int brow = n0 + bn;
    if (brow > p.N - 1) brow = p.N - 1;
    const float* brow_ptr = p.B + (size_t)brow * 1024;

    f32x4 acc[4][4] = {};

    for (int k0 = 0; k0 < 1024; k0 += 64) {
        __syncthreads();
#pragma unroll
        for (int i = 0; i < 4; ++i)
            load_lds16(aptr[i] + k0, (void*)&As[ag_base[i]]);
#pragma unroll
        for (int j = 0; j < 8; ++j) {
            const int kq = bhalf * 8 + j;
            const float4 v = *(const float4*)(brow_ptr + k0 + kq * 4);
            const unsigned px = __builtin_amdgcn_perm(__float_as_uint(v.y), __float_as_uint(v.x), 0x07060302);
            const unsigned pyv = __builtin_amdgcn_perm(__float_as_uint(v.w), __float_as_uint(v.z), 0x07060302);
            const int gran = (kq >> 1) * 128 + bn;
            *(uint2*)&Bs[gran * 8 + (kq & 1) * 4] = make_uint2(px, pyv);
        }
        __syncthreads();

#pragma unroll
        for (int kk = 0; kk < 2; ++kk) {
            const int kgb = kk * 4 + quad;
            short8 af[4], bfr[4];
#pragma unroll
            for (int mi = 0; mi < 4; ++mi)
                af[mi] = *(const short8*)&As[(kgb * 128 + wm + mi * 16 + lane16) * 8];
#pragma unroll
            for (int ni = 0; ni < 4; ++ni)
                bfr[ni] = *(const short8*)&Bs[(kgb * 128 + wn + ni * 16 + lane16) * 8];
#pragma unroll
            for (int mi = 0; mi < 4; ++mi)
#pragma unroll
                for (int ni = 0; ni < 4; ++ni)
                    acc[mi][ni] = __builtin_amdgcn_mfma_f32_16x16x32_bf16(
                        af[mi], bfr[ni], acc[mi][ni], 0, 0, 0);
        }
    }

    // epilogue 1: bf16 Y store
#pragma unroll
    for (int mi = 0; mi < 4; ++mi)
#pragma unroll
        for (int ni = 0; ni < 4; ++ni) {
            const int n = n0 + wn + ni * 16 + lane16;
            if (n < p.ldc) {
#pragma unroll
                for (int r = 0; r < 4; ++r) {
                    const int m = m0 + wm + mi * 16 + quad * 4 + r;
                    const float v = (n < p.nreal) ? acc[mi][ni][r] : 0.f;
                    p.Cbf[(size_t)m * p.ldc + n] = f2bf_rne(v);
                }
            }
        }

    // epilogue 2: fp8 Y store in granule-tile layout (scale x4), via LDS bounce
    float* bounce = (float*)smem;                           // [128][66]
    u64* Yout = (u64*)p.Cf8 + (size_t)mt * 16 * p.Kpad;
    for (int c = 0; c < 2; ++c) {
        const int colbase = n0 + c * 64;
        if (colbase >= p.Kpad) break;
        __syncthreads();
        if ((w & 1) == c) {
#pragma unroll
            for (int mi = 0; mi < 4; ++mi)
#pragma unroll
                for (int ni = 0; ni < 4; ++ni) {
                    const int ncol = ni * 16 + lane16;
                    const bool real = (colbase + ncol) < p.nreal;
#pragma unroll
                    for (int r = 0; r < 4; ++r) {
                        const int m = wm + mi * 16 + quad * 4 + r;
                        bounce[m * 66 + ncol] = real ? acc[mi][ni][r] : 0.f;
                    }
                }
        }
        __syncthreads();
#pragma unroll
        for (int i = 0; i < 4; ++i) {
            const int g = i * 256 + tid;
            const int kgl = g >> 7;
            const int m = g & 127;
            float v[8];
#pragma unroll
            for (int j = 0; j < 8; ++j) v[j] = bounce[m * 66 + kgl * 8 + j];
            Yout[((colbase >> 3) + kgl) * 128 + m] = pack8_fp8(v, 4.0f);
        }
    }
}

// ---------------- pipelined fp8 exp-sum GEMM (3-slot ring, ONE barrier/iter) ----------------
// m233 lesson: in a 2-phase loop the stage+vmcnt+barrier critical path IS the
// cost (r7 occupancy and r8 flush-move both null). With a 3-deep LDS ring the
// second barrier is provably unnecessary: the refill for iteration i+2 targets
// slot (i-1)%3, and arrival at barrier(i) already proves every wave finished
// reading that slot (they read it in compute(i-1), which precedes their
// barrier(i) arrival in program order). So: one barrier + one counted wait per
// iteration, prefetch window ~2.5 iterations, no lgkm bias-snapshot needed
// (flush reads bias slot i%3 while refill writes slot (i+2)%3 — disjoint).
// Wait algebra unchanged: at top of iter i, outstanding = batch(i)+batch(i+1);
// vmcnt(batchsize) drains batch(i) (in-order retirement covers bias/A too).
// LDS: 48K As[3] + 24K Bs[3] + 1.5K bias[3] = 75264 -> 2 blocks/CU.
struct ExpDesc {
    const unsigned char* A;   // fp8 Y, granule-tile layout
    const unsigned char* W;   // fp8 W, granule-tile layout
    const float* bias;        // padded, pre-scaled by log2e
    float* part;              // [G][1024]
    int Kpad; int ksl; int kmask; int gy_begin; int slab;  // slab in 128-row tiles
};

__global__ __launch_bounds__(512) void exp_gemm(ExpDesc d0, ExpDesc d1, ExpDesc d2, ExpDesc d3)
{
    __shared__ u64 As[3][2048];       // 16 KB/slot: [mtHalf 0|1][1024]
    __shared__ u64 Bs[3][1024];       // 8 KB/slot
    __shared__ float biasLds[3][128]; // 512 B/slot

    const int p = blockIdx.x;         // 0..3; handles mt = p and p+4
    const int gy = blockIdx.y;

    ExpDesc d = (gy >= d3.gy_begin) ? d3 : (gy >= d2.gy_begin) ? d2
              : (gy >= d1.gy_begin) ? d1 : d0;

    const int tid = threadIdx.x;      // 0..511
    const int w = tid >> 6;           // 0..7
    const int l = tid & 63;
    const int wmt = w >> 2;           // which mt half (0: p, 1: p+4)
    const int wq = w & 3;
    const int wm = (wq >> 1) * 64;
    const int wn = (wq & 1) * 64;
    const int lane16 = l & 15;
    const int quad = l >> 4;

    const int tiles_begin = (gy - d.gy_begin) * d.slab;
    const int T = d.slab << d.ksl;    // always 16
    const int kmask = d.kmask;
    const int ksl = d.ksl;
    const bool haveA = (kmask != 0);

    const size_t tstride = (size_t)128 * d.Kpad;
    const unsigned char* Abase0 = d.A + (size_t)p * tstride;
    const unsigned char* Abase1 = d.A + (size_t)(p + 4) * tstride;
    const unsigned char* Bbase = d.W + (size_t)tiles_begin * tstride;
    const float* biasBase = d.bias + (size_t)tiles_begin * 128;

    const int so = tid * 16;
    const int bu = (w * 4 + l) * 16;  // bias ring byte offset (lanes 0-3 only)

    // ---- prologue: batches for iterations 0 and 1 -> slots 0, 1 ----
    if (haveA) {
        load_lds16(Abase0 + so, (char*)As[0] + so);
        load_lds16(Abase1 + so, (char*)As[0] + 8192 + so);
        load_lds16(Bbase + so, (char*)Bs[0] + so);
        if (l < 4) load_lds16(biasBase + (bu >> 2), (char*)biasLds + bu);
        load_lds16(Abase0 + 8192 + so, (char*)As[1] + so);
        load_lds16(Abase1 + 8192 + so, (char*)As[1] + 8192 + so);
        load_lds16(Bbase + 8192 + so, (char*)Bs[1] + so);
        if (l < 4) load_lds16(biasBase + (bu >> 2), (char*)biasLds + 512 + bu);
    } else {
        // A fixed: parked in As[0] (drained with batch 0; in-order retirement)
        load_lds16(Abase0 + so, (char*)As[0] + so);
        load_lds16(Abase1 + so, (char*)As[0] + 8192 + so);
        load_lds16(Bbase + so, (char*)Bs[0] + so);
        if (l < 4) load_lds16(biasBase + (bu >> 2), (char*)biasLds + bu);
        load_lds16(Bbase + tstride + so, (char*)Bs[1] + so);
        if (l < 4) load_lds16(biasBase + 128 + (bu >> 2), (char*)biasLds + 512 + bu);
    }

    f32x4 acc[4][4] = {};
    float rowsum[4][4] = {};
    const float c1 = LOG2E / 64.0f;   // undo fp8 scales (4*16) and convert e->2^

    int slot = 0;                     // it % 3
    int ns = 2;                       // (it + 2) % 3
    for (int it = 0; it < T; ++it) {
        // counted wait: drain batch(it), leave batch(it+1) in flight
        if (it + 1 < T) { if (haveA) waitvm<4>(); else waitvm<2>(); }
        else            { waitvm<0>(); }
        __builtin_amdgcn_s_barrier();     // all waves done reading slot ns (= (it-1)%3)
        __builtin_amdgcn_sched_barrier(0);

        // refill slot ns for iteration it+2 (disjoint from slot being read)
        if (it + 2 < T) {
            const int nit = it + 2;
            const int kc = nit & kmask;
            const int tile = nit >> ksl;
            if (haveA) {
                load_lds16(Abase0 + kc * 8192 + so, (char*)As[ns] + so);
                load_lds16(Abase1 + kc * 8192 + so, (char*)As[ns] + 8192 + so);
            }
            load_lds16(Bbase + (size_t)tile * tstride + kc * 8192 + so, (char*)Bs[ns] + so);
            if (l < 4)
                load_lds16(biasBase + (size_t)tile * 128 + (bu >> 2),
                           (char*)biasLds + ns * 512 + bu);
        }

        const u64* Ar = (haveA ? As[slot] : As[0]) + wmt * 1024;
        const u64* Br = Bs[slot];
#pragma unroll
        for (int ks = 0; ks < 2; ++ks) {
            u64 af[4], bfr[4];
#pragma unroll
            for (int mi = 0; mi < 4; ++mi)
                af[mi] = Ar[(ks * 4 + quad) * 128 + wm + mi * 16 + lane16];
#pragma unroll
            for (int ni = 0; ni < 4; ++ni)
                bfr[ni] = Br[(ks * 4 + quad) * 128 + wn + ni * 16 + lane16];
#pragma unroll
            for (int mi = 0; mi < 4; ++mi)
#pragma unroll
                for (int ni = 0; ni < 4; ++ni)
                    acc[mi][ni] = __builtin_amdgcn_mfma_f32_16x16x32_fp8_fp8(
                        (long)af[mi], (long)bfr[ni], acc[mi][ni], 0, 0, 0);
        }

        if ((it & kmask) == kmask) {
            // bias for tile (it>>ksl) sits in ring slot it%3; refill above
            // targets slot (it+2)%3 -> no overlap, no extra sync needed.
            float biasc[4];
#pragma unroll
            for (int ni = 0; ni < 4; ++ni)
                biasc[ni] = biasLds[slot][wn + ni * 16 + lane16];
#pragma unroll
            for (int mi = 0; mi < 4; ++mi)
#pragma unroll
                for (int r = 0; r < 4; ++r) {
                    float s = exp2f(fmaf(acc[mi][0][r], c1, biasc[0]))
                            + exp2f(fmaf(acc[mi][1][r], c1, biasc[1]))
                            + exp2f(fmaf(acc[mi][2][r], c1, biasc[2]))
                            + exp2f(fmaf(acc[mi][3][r], c1, biasc[3]));
                    rowsum[mi][r] += s;
                }
#pragma unroll
            for (int mi = 0; mi < 4; ++mi)
#pragma unroll
                for (int ni = 0; ni < 4; ++ni)
                    acc[mi][ni] = (f32x4){0.f, 0.f, 0.f, 0.f};
        }

        slot = (slot == 2) ? 0 : slot + 1;
        ns   = (ns   == 2) ? 0 : ns   + 1;
    }

#pragma unroll
    for (int off = 1; off < 16; off <<= 1)
#pragma unroll
        for (int mi = 0; mi < 4; ++mi)
#pragma unroll
            for (int r = 0; r < 4; ++r)
                rowsum[mi][r] += __shfl_xor(rowsum[mi][r], off, 64);

    __syncthreads();
    float* buf = (float*)As;   // [2][128][2] overlay; As is dead here
    if (lane16 == 0) {
#pragma unroll
        for (int mi = 0; mi < 4; ++mi)
#pragma unroll
            for (int r = 0; r < 4; ++r)
                buf[(wmt * 128 + wm + mi * 16 + quad * 4 + r) * 2 + (wn >> 6)] = rowsum[mi][r];
    }
    __syncthreads();
    if (tid < 256) {
        const int row = tid & 127;
        const int mtreal = p + (tid >> 7) * 4;
        d.part[(size_t)(gy - d.gy_begin) * 1024 + mtreal * 128 + row] =
            buf[tid * 2 + 0] + buf[tid * 2 + 1];
    }
}

// ---------------- fused partial-reduce + target-logit extraction ----------------
__global__ void redext(const float* __restrict__ p0, const float* __restrict__ p1,
                       const float* __restrict__ p2, const float* __restrict__ p3,
                       float* __restrict__ S,
                       const unsigned short* __restrict__ Y0, const unsigned short* __restrict__ Y1,
                       const unsigned short* __restrict__ Y2, const unsigned short* __restrict__ Y3,
                       const int* __restrict__ target,
                       const float* __restrict__ W0, const float* __restrict__ b0,
                       const float* __restrict__ W1, const float* __restrict__ b1,
                       const float* __restrict__ W2, const float* __restrict__ b2,
                       const float* __restrict__ W3, const float* __restrict__ b3,
                       const float* __restrict__ cw, const float* __restrict__ cb,
                       float* __restrict__ headlogit, float* __restrict__ taillogit)
{
    if (blockIdx.x < 16) {
        const int idx = blockIdx.x * 256 + threadIdx.x;   // [0,4096)
        const int c = idx >> 10, m = idx & 1023;
        const float* p = (c == 0) ? p0 : (c == 1) ? p1 : (c == 2) ? p2 : p3;
        const int G = (c == 0) ? 157 : (c == 1) ? 40 : (c == 2) ? 79 : 34;
        float s = 0.f;
        for (int y = 0; y < G; ++y) s += p[(size_t)y * 1024 + m];
        S[idx] = s;
        return;
    }
    const int token = (blockIdx.x - 16) * 4 + (threadIdx.x >> 6);
    const int lane = threadIdx.x & 63;
    const int tgt = target[token];
    const int ci = (tgt < 20000) ? 0 : (tgt < 40000) ? 1 : (tgt < 200000) ? 2 : 3;

    {
        const int h = (ci == 0) ? tgt : (20000 + ci - 1);
        const float* row;
        float bb;
        if (h < 20000) { row = W0 + (size_t)h * 1024; bb = b0[h]; }
        else           { row = cw + (size_t)(h - 20000) * 1024; bb = cb[h - 20000]; }
        const unsigned short* y = Y0 + (size_t)token * 1024;
        float s = 0.f;
        for (int k = lane; k < 1024; k += 64) s += bf2f(y[k]) * row[k];
#pragma unroll
        for (int off = 1; off < 64; off <<= 1) s += __shfl_xor(s, off, 64);
        if (lane == 0) headlogit[token] = s + bb;
    }

    float tl = 0.f;
    if (ci > 0) {
        const unsigned short* Y; const float* W; const float* b; int K, ldy, lidx;
        if (ci == 1)      { Y = Y1; W = W1; b = b1; K = 256; ldy = 256; lidx = 20000; }
        else if (ci == 2) { Y = Y2; W = W2; b = b2; K = 64;  ldy = 64;  lidx = 40000; }
        else              { Y = Y3; W = W3; b = b3; K = 16;  ldy = 64;  lidx = 200000; }
        const int r = tgt - lidx;
        const unsigned short* y = Y + (size_t)token * ldy;
        const float* row = W + (size_t)r * K;
        float s = 0.f;
        for (int k = lane; k < K; k += 64) s += bf2f(y[k]) * row[k];
#pragma unroll
        for (int off = 1; off < 64; off <<= 1) s += __shfl_xor(s, off, 64);
        tl = s + b[r];
    }
    if (lane == 0) taillogit[token] = tl;
}

__global__ void finalize_kernel(const float* __restrict__ S,
                                const int* __restrict__ target,
                                const float* __restrict__ headlogit,
                                const float* __restrict__ taillogit,
                                float* __restrict__ out)
{
    __shared__ float red[256];
    const int tid = threadIdx.x;
    float acc = 0.f;
    for (int token = tid; token < 1024; token += 256) {
        const int tgt = target[token];
        const int ci = (tgt < 20000) ? 0 : (tgt < 40000) ? 1 : (tgt < 200000) ? 2 : 3;
        float lp = headlogit[token] - logf(S[token]);
        if (ci > 0)
            lp += taillogit[token] - logf(S[ci * 1024 + token]);
        acc -= lp;
    }
    red[tid] = acc;
    __syncthreads();
    for (int s = 128; s > 0; s >>= 1) {
        if (tid < s) red[tid] += red[tid + s];
        __syncthreads();
    }
    if (tid == 0) out[0] = red[0] * (1.0f / 1024.0f);
}

extern "C" void kernel_launch(void* const* d_in, const int* in_sizes, int n_in,
                              void* d_out, int out_size, void* d_ws, size_t ws_size,
                              hipStream_t stream)
{
    const float* hidden = (const float*)d_in[0];
    const int*   target = (const int*)d_in[1];
    const float* W0 = (const float*)d_in[2];  const float* b0 = (const float*)d_in[3];  const float* P0 = (const float*)d_in[4];
    const float* W1 = (const float*)d_in[5];  const float* b1 = (const float*)d_in[6];  const float* P1 = (const float*)d_in[7];
    const float* W2 = (const float*)d_in[8];  const float* b2 = (const float*)d_in[9];  const float* P2 = (const float*)d_in[10];
    const float* W3 = (const float*)d_in[11]; const float* b3 = (const float*)d_in[12]; const float* P3 = (const float*)d_in[13];
    const float* cw = (const float*)d_in[14]; const float* cb = (const float*)d_in[15];
    float* out = (float*)d_out;

    // ---- workspace layout (byte offsets) ----
    unsigned char* ws = (unsigned char*)d_ws;
    unsigned short* h_bf = (unsigned short*)ws;                       //  2,097,152 B (overlaid later)
    unsigned short* Y0bf = (unsigned short*)(ws + 2097152);           //  2,097,152
    unsigned short* Y1bf = (unsigned short*)(ws + 4194304);           //    524,288
    unsigned short* Y2bf = (unsigned short*)(ws + 4718592);           //    131,072
    unsigned short* Y3bf = (unsigned short*)(ws + 4849664);           //    131,072
    unsigned char* Y0f8 = ws + 4980736;                               //  1,048,576
    unsigned char* Y1f8 = ws + 6029312;                               //    262,144
    unsigned char* Y2f8 = ws + 6291456;                               //     65,536
    unsigned char* Y3f8 = ws + 6356992;                               //     65,536
    unsigned char* Wb0 = ws + 6422528;                                // 20,578,304 (157 tiles)
    unsigned char* Wb1 = ws + 27000832;                               //  5,242,880 (160 tiles)
    unsigned char* Wb2 = ws + 32243712;                               // 10,354,688 (1264 tiles)
    unsigned char* Wb3 = ws + 42598400;                               //  4,456,448 (544 tiles)
    float* bp = (float*)(ws + 47054848);                              //  1,088,000 (272000 f)

    // overlays on h_bf (dead after prepproj)
    float* part0 = (float*)ws;                     // 157*4 KB
    float* part1 = part0 + (size_t)157 * 1024;     //  40*4 KB
    float* part2 = part1 + (size_t)40 * 1024;      //  79*4 KB
    float* part3 = part2 + (size_t)79 * 1024;      //  34*4 KB
    float* S = part3 + (size_t)34 * 1024;          // 4*1024
    float* headlogit = S + 4096;
    float* taillogit = headlogit + 1024;

    cvt_h<<<1024, 256, 0, stream>>>(hidden, h_bf);

    ProjDesc pr0 = { P0, Y0bf, Y0f8, 1024, 1024, 1024, 1024, 0 };
    ProjDesc pr1 = { P1, Y1bf, Y1f8, 256,  256,  256,  256,  8 };
    ProjDesc pr2 = { P2, Y2bf, Y2f8, 64,   64,   64,   64,   10 };
    ProjDesc pr3 = { P3, Y3bf, Y3f8, 64,   16,   16,   64,   11 };
    prepproj<<<2048, 256, 0, stream>>>(h_bf, pr0, pr1, pr2, pr3,
                                       W0, cw, W1, W2, W3,
                                       b0, cb, b1, b2, b3,
                                       Wb0, Wb1, Wb2, Wb3, bp);

    ExpDesc d0 = { Y0f8, Wb0, bp,          part0, 1024, 4, 15, 0,   1 };
    ExpDesc d1 = { Y1f8, Wb1, bp + 20096,  part1, 256,  2, 3,  157, 4 };
    ExpDesc d2 = { Y2f8, Wb2, bp + 40576,  part2, 64,   0, 0,  197, 16 };
    ExpDesc d3 = { Y3f8, Wb3, bp + 202368, part3, 64,   0, 0,  276, 16 };
    exp_gemm<<<dim3(4, 310), 512, 0, stream>>>(d0, d1, d2, d3);

    redext<<<272, 256, 0, stream>>>(part0, part1, part2, part3, S,
                                    Y0bf, Y1bf, Y2bf, Y3bf, target,
                                    W0, b0, W1, b1, W2, b2, W3, b3,
                                    cw, cb, headlogit, taillogit);

    finalize_kernel<<<1, 256, 0, stream>>>(S, target, headlogit, taillogit, out);
}

// Round 11
// 352.765 us; speedup vs baseline: 1.1158x; 1.1158x over previous
//
#include <hip/hip_runtime.h>
#include <math.h>

typedef short short8 __attribute__((ext_vector_type(8)));
typedef float f32x4 __attribute__((ext_vector_type(4)));
typedef unsigned long long u64;

#define LOG2E 1.4426950408889634f

// raw hardware 2^x (v_exp_f32): bit-identical to OCML exp2f for x >= -126
// (our real args are |x|<10; pad rows x=-1.4e30 -> 0.0 on both paths).
// Skips OCML's ~5-instr denormal-fixup per call (~20us chip-wide here).
#if __has_builtin(__builtin_amdgcn_exp2f)
#define EXP2(x) __builtin_amdgcn_exp2f(x)
#else
#define EXP2(x) exp2f(x)
#endif

__device__ __forceinline__ unsigned short f2bf_rne(float f) {
    unsigned u = __float_as_uint(f);
    unsigned r = (u + 0x7fff + ((u >> 16) & 1)) >> 16;
    return (unsigned short)r;
}
__device__ __forceinline__ float bf2f(unsigned short h) {
    return __uint_as_float(((unsigned)h) << 16);
}
__device__ __forceinline__ void load_lds16(const void* g, void* l) {
    __builtin_amdgcn_global_load_lds((const __attribute__((address_space(1))) void*)g,
                                     (__attribute__((address_space(3))) void*)l,
                                     16, 0, 0);
}
template<int N>
__device__ __forceinline__ void waitvm() {
    asm volatile("s_waitcnt vmcnt(%0)" :: "n"(N) : "memory");
}
// 8 fp32 -> 8 fp8 e4m3 (RNE, saturating), scaled
__device__ __forceinline__ u64 pack8_fp8(const float* v, float s) {
    int lo = 0, hi = 0;
    lo = __builtin_amdgcn_cvt_pk_fp8_f32(v[0] * s, v[1] * s, lo, false);
    lo = __builtin_amdgcn_cvt_pk_fp8_f32(v[2] * s, v[3] * s, lo, true);
    hi = __builtin_amdgcn_cvt_pk_fp8_f32(v[4] * s, v[5] * s, hi, false);
    hi = __builtin_amdgcn_cvt_pk_fp8_f32(v[6] * s, v[7] * s, hi, true);
    return (u64)(unsigned)lo | ((u64)(unsigned)hi << 32);
}

// ---------------- cvt hidden fp32 -> bf16 ----------------
__global__ void cvt_h(const float* __restrict__ in, unsigned short* __restrict__ out)
{
    const int i = blockIdx.x * 256 + threadIdx.x;   // one float4 quad each
    const float4 v = *(const float4*)(in + (size_t)i * 4);
    ushort4 h;
    h.x = f2bf_rne(v.x); h.y = f2bf_rne(v.y);
    h.z = f2bf_rne(v.z); h.w = f2bf_rne(v.w);
    *(ushort4*)(out + (size_t)i * 4) = h;
}

// ---------------- fused prep (weights->fp8 swizzle + biases) + projections ----------------
// Convert path: panel-based LDS transpose (r9) — both HBM streams contiguous.
struct ProjDesc {
    const float* B;            // fp32 P matrix [N][1024]
    unsigned short* Cbf;       // bf16 Y [1024][ldc]
    unsigned char* Cf8;        // fp8 Y, granule-tile layout, Kpad cols
    int ldc; int nreal; int N; int Kpad; int gy_begin;
};

__global__ __launch_bounds__(256) void prepproj(
    const unsigned short* __restrict__ A,   // h_bf [1024][1024]
    ProjDesc p0, ProjDesc p1, ProjDesc p2, ProjDesc p3,
    const float* __restrict__ W0, const float* __restrict__ cw,
    const float* __restrict__ W1, const float* __restrict__ W2,
    const float* __restrict__ W3,
    const float* __restrict__ b0, const float* __restrict__ cb,
    const float* __restrict__ b1, const float* __restrict__ b2,
    const float* __restrict__ b3,
    unsigned char* __restrict__ Wb0, unsigned char* __restrict__ Wb1,
    unsigned char* __restrict__ Wb2, unsigned char* __restrict__ Wb3,
    float* __restrict__ bp)
{
    __shared__ char smem[34816];

    const int tid = threadIdx.x;
    const int bx = blockIdx.x;

    if (bx >= 96) {
        // ---------- convert path: panel-based LDS transpose ----------
        u64* lds = (u64*)smem;                 // [32][130] u64 = 33280 B
        const int NP = 2596;
        const int nconv = gridDim.x - 96;
        for (int pn = bx - 96; pn < NP; pn += nconv) {
            __syncthreads();                   // LDS reuse across panels
            if (pn < 788) {
                // ---- W0 / W1: 128 rows x 256 cols, KG=32 ----
                const bool isW0 = (pn < 628);
                const int tile = isW0 ? (pn >> 2) : (pn - 628);
                const int c0 = isW0 ? (pn & 3) * 256 : 0;
                unsigned char* dstm = isW0 ? Wb0 : Wb1;
                const int tstride = isW0 ? 131072 : 32768;
#pragma unroll
                for (int rp = 0; rp < 8; ++rp) {
                    const int row = rp * 16 + (tid >> 4);
                    const int colf = (tid & 15) * 16;
                    const int row_g = tile * 128 + row;
                    const float* s = nullptr;
                    if (isW0) {
                        if (row_g < 20000)      s = W0 + (size_t)row_g * 1024 + c0 + colf;
                        else if (row_g < 20003) s = cw + (size_t)(row_g - 20000) * 1024 + c0 + colf;
                    } else {
                        if (row_g < 20000)      s = W1 + (size_t)row_g * 256 + colf;
                    }
                    float f[16];
                    if (s) {
#pragma unroll
                        for (int q = 0; q < 4; ++q) {
                            const float4 v = *(const float4*)(s + q * 4);
                            f[q * 4 + 0] = v.x; f[q * 4 + 1] = v.y;
                            f[q * 4 + 2] = v.z; f[q * 4 + 3] = v.w;
                        }
                    } else {
#pragma unroll
                        for (int q = 0; q < 16; ++q) f[q] = 0.f;
                    }
                    const int kg = (tid & 15) * 2;
                    lds[kg * 130 + row]       = pack8_fp8(f,     16.0f);
                    lds[(kg + 1) * 130 + row] = pack8_fp8(f + 8, 16.0f);
                }
                __syncthreads();
                u64* dst = (u64*)(dstm + (size_t)tile * tstride) + (size_t)(c0 >> 3) * 128;
#pragma unroll
                for (int i = 0; i < 16; ++i) {
                    const int lin = i * 256 + tid;
                    const int kg = lin >> 7, r = lin & 127;
                    dst[lin] = lds[kg * 130 + r];
                }
            } else if (pn < 2052) {
                // ---- W2: 128 rows x 64 cols, KG=8 ----
                const int tile = pn - 788;
#pragma unroll
                for (int rp = 0; rp < 2; ++rp) {
                    const int row = rp * 64 + (tid >> 2);
                    const int colf = (tid & 3) * 16;
                    const int row_g = tile * 128 + row;
                    const float* s = (row_g < 160000) ? W2 + (size_t)row_g * 64 + colf : nullptr;
                    float f[16];
                    if (s) {
#pragma unroll
                        for (int q = 0; q < 4; ++q) {
                            const float4 v = *(const float4*)(s + q * 4);
                            f[q * 4 + 0] = v.x; f[q * 4 + 1] = v.y;
                            f[q * 4 + 2] = v.z; f[q * 4 + 3] = v.w;
                        }
                    } else {
#pragma unroll
                        for (int q = 0; q < 16; ++q) f[q] = 0.f;
                    }
                    const int kg = (tid & 3) * 2;
                    lds[kg * 130 + row]       = pack8_fp8(f,     16.0f);
                    lds[(kg + 1) * 130 + row] = pack8_fp8(f + 8, 16.0f);
                }
                __syncthreads();
                u64* dst = (u64*)(Wb2 + (size_t)tile * 8192);
#pragma unroll
                for (int i = 0; i < 4; ++i) {
                    const int lin = i * 256 + tid;
                    const int kg = lin >> 7, r = lin & 127;
                    dst[lin] = lds[kg * 130 + r];
                }
            } else {
                // ---- W3: 128 rows x 16 real cols; out kg 0..7, kg>=2 zero ----
                const int tile = pn - 2052;
                if (tid < 128) {
                    const int row = tid;
                    const int row_g = tile * 128 + row;
                    const float* s = (row_g < 67735) ? W3 + (size_t)row_g * 16 : nullptr;
                    float f[16];
                    if (s) {
#pragma unroll
                        for (int q = 0; q < 4; ++q) {
                            const float4 v = *(const float4*)(s + q * 4);
                            f[q * 4 + 0] = v.x; f[q * 4 + 1] = v.y;
                            f[q * 4 + 2] = v.z; f[q * 4 + 3] = v.w;
                        }
                    } else {
#pragma unroll
                        for (int q = 0; q < 16; ++q) f[q] = 0.f;
                    }
                    lds[row]       = pack8_fp8(f,     16.0f);
                    lds[130 + row] = pack8_fp8(f + 8, 16.0f);
                }
                __syncthreads();
                u64* dst = (u64*)(Wb3 + (size_t)tile * 8192);
#pragma unroll
                for (int i = 0; i < 4; ++i) {
                    const int lin = i * 256 + tid;
                    const int kg = lin >> 7, r = lin & 127;
                    dst[lin] = (kg < 2) ? lds[kg * 130 + r] : 0ull;
                }
            }
        }

        // ---------- padded biases, pre-scaled by log2e; pad rows -> -1e30 ----------
        const unsigned BN = 68000u;   // float4 units
        const unsigned stride = (gridDim.x - 96) * 256u;
        for (unsigned u = (bx - 96) * 256u + tid; u < BN; u += stride) {
            const unsigned idx0 = u * 4u;
            float e[4];
#pragma unroll
            for (int j = 0; j < 4; ++j) {
                const unsigned idx = idx0 + j;
                float v;
                if (idx < 20096u) {
                    v = (idx < 20000u) ? b0[idx] * LOG2E
                      : (idx < 20003u) ? cb[idx - 20000u] * LOG2E : -1e30f;
                } else if (idx < 40576u) {
                    const unsigned i1 = idx - 20096u;
                    v = (i1 < 20000u) ? b1[i1] * LOG2E : -1e30f;
                } else if (idx < 202368u) {
                    const unsigned i2 = idx - 40576u;
                    v = (i2 < 160000u) ? b2[i2] * LOG2E : -1e30f;
                } else {
                    const unsigned i3 = idx - 202368u;
                    v = (i3 < 67735u) ? b3[i3] * LOG2E : -1e30f;
                }
                e[j] = v;
            }
            *(float4*)(bp + idx0) = make_float4(e[0], e[1], e[2], e[3]);
        }
        return;
    }

    // ---------- projection GEMM path ----------
    unsigned short* As = (unsigned short*)smem;            // [8192] bf16
    unsigned short* Bs = (unsigned short*)(smem + 16384);  // [8192] bf16

    const int mt = bx & 7;
    const int py = bx >> 3;
    ProjDesc p = (py >= p3.gy_begin) ? p3 : (py >= p2.gy_begin) ? p2
               : (py >= p1.gy_begin) ? p1 : p0;

    const int w = tid >> 6;
    const int l = tid & 63;
    const int m0 = mt * 128;
    const int n0 = (py - p.gy_begin) * 128;
    const int wm = (w >> 1) * 64;
    const int wn = (w & 1) * 64;
    const int lane16 = l & 15;
    const int quad = l >> 4;

    const unsigned short* aptr[4];
    int ag_base[4];
#pragma unroll
    for (int i = 0; i < 4; ++i) {
        const int g = w * 256 + i * 64 + l;
        aptr[i] = A + (size_t)(m0 + (g & 127)) * 1024 + (g >> 7) * 8;
        ag_base[i] = (w * 256 + i * 64) * 8;
    }

    const int bn = tid >> 1;
    const int bhalf = tid & 1;
    int brow = n0 + bn;
    if (brow > p.N - 1) brow = p.N - 1;
    const float* brow_ptr = p.B + (size_t)brow * 1024;

    f32x4 acc[4][4] = {};

    for (int k0 = 0; k0 < 1024; k0 += 64) {
        __syncthreads();
#pragma unroll
        for (int i = 0; i < 4; ++i)
            load_lds16(aptr[i] + k0, (void*)&As[ag_base[i]]);
#pragma unroll
        for (int j = 0; j < 8; ++j) {
            const int kq = bhalf * 8 + j;
            const float4 v = *(const float4*)(brow_ptr + k0 + kq * 4);
            const unsigned px = __builtin_amdgcn_perm(__float_as_uint(v.y), __float_as_uint(v.x), 0x07060302);
            const unsigned pyv = __builtin_amdgcn_perm(__float_as_uint(v.w), __float_as_uint(v.z), 0x07060302);
            const int gran = (kq >> 1) * 128 + bn;
            *(uint2*)&Bs[gran * 8 + (kq & 1) * 4] = make_uint2(px, pyv);
        }
        __syncthreads();

#pragma unroll
        for (int kk = 0; kk < 2; ++kk) {
            const int kgb = kk * 4 + quad;
            short8 af[4], bfr[4];
#pragma unroll
            for (int mi = 0; mi < 4; ++mi)
                af[mi] = *(const short8*)&As[(kgb * 128 + wm + mi * 16 + lane16) * 8];
#pragma unroll
            for (int ni = 0; ni < 4; ++ni)
                bfr[ni] = *(const short8*)&Bs[(kgb * 128 + wn + ni * 16 + lane16) * 8];
#pragma unroll
            for (int mi = 0; mi < 4; ++mi)
#pragma unroll
                for (int ni = 0; ni < 4; ++ni)
                    acc[mi][ni] = __builtin_amdgcn_mfma_f32_16x16x32_bf16(
                        af[mi], bfr[ni], acc[mi][ni], 0, 0, 0);
        }
    }

    // epilogue 1: bf16 Y store
#pragma unroll
    for (int mi = 0; mi < 4; ++mi)
#pragma unroll
        for (int ni = 0; ni < 4; ++ni) {
            const int n = n0 + wn + ni * 16 + lane16;
            if (n < p.ldc) {
#pragma unroll
                for (int r = 0; r < 4; ++r) {
                    const int m = m0 + wm + mi * 16 + quad * 4 + r;
                    const float v = (n < p.nreal) ? acc[mi][ni][r] : 0.f;
                    p.Cbf[(size_t)m * p.ldc + n] = f2bf_rne(v);
                }
            }
        }

    // epilogue 2: fp8 Y store in granule-tile layout (scale x4), via LDS bounce
    float* bounce = (float*)smem;                           // [128][66]
    u64* Yout = (u64*)p.Cf8 + (size_t)mt * 16 * p.Kpad;
    for (int c = 0; c < 2; ++c) {
        const int colbase = n0 + c * 64;
        if (colbase >= p.Kpad) break;
        __syncthreads();
        if ((w & 1) == c) {
#pragma unroll
            for (int mi = 0; mi < 4; ++mi)
#pragma unroll
                for (int ni = 0; ni < 4; ++ni) {
                    const int ncol = ni * 16 + lane16;
                    const bool real = (colbase + ncol) < p.nreal;
#pragma unroll
                    for (int r = 0; r < 4; ++r) {
                        const int m = wm + mi * 16 + quad * 4 + r;
                        bounce[m * 66 + ncol] = real ? acc[mi][ni][r] : 0.f;
                    }
                }
        }
        __syncthreads();
#pragma unroll
        for (int i = 0; i < 4; ++i) {
            const int g = i * 256 + tid;
            const int kgl = g >> 7;
            const int m = g & 127;
            float v[8];
#pragma unroll
            for (int j = 0; j < 8; ++j) v[j] = bounce[m * 66 + kgl * 8 + j];
            Yout[((colbase >> 3) + kgl) * 128 + m] = pack8_fp8(v, 4.0f);
        }
    }
}

// ---------------- pipelined fp8 exp-sum GEMM (3-slot ring, raw v_exp_f32) ----------------
// r10 structure (3-slot ring, one barrier/iter, counted vmcnt) with exp2f
// replaced by the hardware builtin. Four scheduling restructures (occupancy,
// flush placement, barrier removal) were all null at ~143us; the counter
// accounting (VALUBusy 60% = 86us vs ~76us of inventoried issue work) says
// the kernel is issue-WORK-bound, so cut instructions, not reorder them.
struct ExpDesc {
    const unsigned char* A;   // fp8 Y, granule-tile layout
    const unsigned char* W;   // fp8 W, granule-tile layout
    const float* bias;        // padded, pre-scaled by log2e
    float* part;              // [G][1024]
    int Kpad; int ksl; int kmask; int gy_begin; int slab;  // slab in 128-row tiles
};

__global__ __launch_bounds__(512) void exp_gemm(ExpDesc d0, ExpDesc d1, ExpDesc d2, ExpDesc d3)
{
    __shared__ u64 As[3][2048];       // 16 KB/slot: [mtHalf 0|1][1024]
    __shared__ u64 Bs[3][1024];       // 8 KB/slot
    __shared__ float biasLds[3][128]; // 512 B/slot

    const int p = blockIdx.x;         // 0..3; handles mt = p and p+4
    const int gy = blockIdx.y;

    ExpDesc d = (gy >= d3.gy_begin) ? d3 : (gy >= d2.gy_begin) ? d2
              : (gy >= d1.gy_begin) ? d1 : d0;

    const int tid = threadIdx.x;      // 0..511
    const int w = tid >> 6;           // 0..7
    const int l = tid & 63;
    const int wmt = w >> 2;           // which mt half (0: p, 1: p+4)
    const int wq = w & 3;
    const int wm = (wq >> 1) * 64;
    const int wn = (wq & 1) * 64;
    const int lane16 = l & 15;
    const int quad = l >> 4;

    const int tiles_begin = (gy - d.gy_begin) * d.slab;
    const int T = d.slab << d.ksl;    // always 16
    const int kmask = d.kmask;
    const int ksl = d.ksl;
    const bool haveA = (kmask != 0);

    const size_t tstride = (size_t)128 * d.Kpad;
    const unsigned char* Abase0 = d.A + (size_t)p * tstride;
    const unsigned char* Abase1 = d.A + (size_t)(p + 4) * tstride;
    const unsigned char* Bbase = d.W + (size_t)tiles_begin * tstride;
    const float* biasBase = d.bias + (size_t)tiles_begin * 128;

    const int so = tid * 16;
    const int bu = (w * 4 + l) * 16;  // bias ring byte offset (lanes 0-3 only)

    // ---- prologue: batches for iterations 0 and 1 -> slots 0, 1 ----
    if (haveA) {
        load_lds16(Abase0 + so, (char*)As[0] + so);
        load_lds16(Abase1 + so, (char*)As[0] + 8192 + so);
        load_lds16(Bbase + so, (char*)Bs[0] + so);
        if (l < 4) load_lds16(biasBase + (bu >> 2), (char*)biasLds + bu);
        load_lds16(Abase0 + 8192 + so, (char*)As[1] + so);
        load_lds16(Abase1 + 8192 + so, (char*)As[1] + 8192 + so);
        load_lds16(Bbase + 8192 + so, (char*)Bs[1] + so);
        if (l < 4) load_lds16(biasBase + (bu >> 2), (char*)biasLds + 512 + bu);
    } else {
        // A fixed: parked in As[0] (drained with batch 0; in-order retirement)
        load_lds16(Abase0 + so, (char*)As[0] + so);
        load_lds16(Abase1 + so, (char*)As[0] + 8192 + so);
        load_lds16(Bbase + so, (char*)Bs[0] + so);
        if (l < 4) load_lds16(biasBase + (bu >> 2), (char*)biasLds + bu);
        load_lds16(Bbase + tstride + so, (char*)Bs[1] + so);
        if (l < 4) load_lds16(biasBase + 128 + (bu >> 2), (char*)biasLds + 512 + bu);
    }

    f32x4 acc[4][4] = {};
    float rowsum[4][4] = {};
    const float c1 = LOG2E / 64.0f;   // undo fp8 scales (4*16) and convert e->2^

    int slot = 0;                     // it % 3
    int ns = 2;                       // (it + 2) % 3
    for (int it = 0; it < T; ++it) {
        // counted wait: drain batch(it), leave batch(it+1) in flight
        if (it + 1 < T) { if (haveA) waitvm<4>(); else waitvm<2>(); }
        else            { waitvm<0>(); }
        __builtin_amdgcn_s_barrier();     // all waves done reading slot ns (= (it-1)%3)
        __builtin_amdgcn_sched_barrier(0);

        // refill slot ns for iteration it+2 (disjoint from slot being read)
        if (it + 2 < T) {
            const int nit = it + 2;
            const int kc = nit & kmask;
            const int tile = nit >> ksl;
            if (haveA) {
                load_lds16(Abase0 + kc * 8192 + so, (char*)As[ns] + so);
                load_lds16(Abase1 + kc * 8192 + so, (char*)As[ns] + 8192 + so);
            }
            load_lds16(Bbase + (size_t)tile * tstride + kc * 8192 + so, (char*)Bs[ns] + so);
            if (l < 4)
                load_lds16(biasBase + (size_t)tile * 128 + (bu >> 2),
                           (char*)biasLds + ns * 512 + bu);
        }

        const u64* Ar = (haveA ? As[slot] : As[0]) + wmt * 1024;
        const u64* Br = Bs[slot];
#pragma unroll
        for (int ks = 0; ks < 2; ++ks) {
            u64 af[4], bfr[4];
#pragma unroll
            for (int mi = 0; mi < 4; ++mi)
                af[mi] = Ar[(ks * 4 + quad) * 128 + wm + mi * 16 + lane16];
#pragma unroll
            for (int ni = 0; ni < 4; ++ni)
                bfr[ni] = Br[(ks * 4 + quad) * 128 + wn + ni * 16 + lane16];
#pragma unroll
            for (int mi = 0; mi < 4; ++mi)
#pragma unroll
                for (int ni = 0; ni < 4; ++ni)
                    acc[mi][ni] = __builtin_amdgcn_mfma_f32_16x16x32_fp8_fp8(
                        (long)af[mi], (long)bfr[ni], acc[mi][ni], 0, 0, 0);
        }

        if ((it & kmask) == kmask) {
            // bias for tile (it>>ksl) sits in ring slot it%3; refill above
            // targets slot (it+2)%3 -> no overlap, no extra sync needed.
            float biasc[4];
#pragma unroll
            for (int ni = 0; ni < 4; ++ni)
                biasc[ni] = biasLds[slot][wn + ni * 16 + lane16];
#pragma unroll
            for (int mi = 0; mi < 4; ++mi)
#pragma unroll
                for (int r = 0; r < 4; ++r) {
                    float s = EXP2(fmaf(acc[mi][0][r], c1, biasc[0]))
                            + EXP2(fmaf(acc[mi][1][r], c1, biasc[1]))
                            + EXP2(fmaf(acc[mi][2][r], c1, biasc[2]))
                            + EXP2(fmaf(acc[mi][3][r], c1, biasc[3]));
                    rowsum[mi][r] += s;
                }
#pragma unroll
            for (int mi = 0; mi < 4; ++mi)
#pragma unroll
                for (int ni = 0; ni < 4; ++ni)
                    acc[mi][ni] = (f32x4){0.f, 0.f, 0.f, 0.f};
        }

        slot = (slot == 2) ? 0 : slot + 1;
        ns   = (ns   == 2) ? 0 : ns   + 1;
    }

#pragma unroll
    for (int off = 1; off < 16; off <<= 1)
#pragma unroll
        for (int mi = 0; mi < 4; ++mi)
#pragma unroll
            for (int r = 0; r < 4; ++r)
                rowsum[mi][r] += __shfl_xor(rowsum[mi][r], off, 64);

    __syncthreads();
    float* buf = (float*)As;   // [2][128][2] overlay; As is dead here
    if (lane16 == 0) {
#pragma unroll
        for (int mi = 0; mi < 4; ++mi)
#pragma unroll
            for (int r = 0; r < 4; ++r)
                buf[(wmt * 128 + wm + mi * 16 + quad * 4 + r) * 2 + (wn >> 6)] = rowsum[mi][r];
    }
    __syncthreads();
    if (tid < 256) {
        const int row = tid & 127;
        const int mtreal = p + (tid >> 7) * 4;
        d.part[(size_t)(gy - d.gy_begin) * 1024 + mtreal * 128 + row] =
            buf[tid * 2 + 0] + buf[tid * 2 + 1];
    }
}

// ---------------- fused partial-reduce + target-logit extraction ----------------
__global__ void redext(const float* __restrict__ p0, const float* __restrict__ p1,
                       const float* __restrict__ p2, const float* __restrict__ p3,
                       float* __restrict__ S,
                       const unsigned short* __restrict__ Y0, const unsigned short* __restrict__ Y1,
                       const unsigned short* __restrict__ Y2, const unsigned short* __restrict__ Y3,
                       const int* __restrict__ target,
                       const float* __restrict__ W0, const float* __restrict__ b0,
                       const float* __restrict__ W1, const float* __restrict__ b1,
                       const float* __restrict__ W2, const float* __restrict__ b2,
                       const float* __restrict__ W3, const float* __restrict__ b3,
                       const float* __restrict__ cw, const float* __restrict__ cb,
                       float* __restrict__ headlogit, float* __restrict__ taillogit)
{
    if (blockIdx.x < 16) {
        const int idx = blockIdx.x * 256 + threadIdx.x;   // [0,4096)
        const int c = idx >> 10, m = idx & 1023;
        const float* p = (c == 0) ? p0 : (c == 1) ? p1 : (c == 2) ? p2 : p3;
        const int G = (c == 0) ? 157 : (c == 1) ? 40 : (c == 2) ? 79 : 34;
        float s = 0.f;
        for (int y = 0; y < G; ++y) s += p[(size_t)y * 1024 + m];
        S[idx] = s;
        return;
    }
    const int token = (blockIdx.x - 16) * 4 + (threadIdx.x >> 6);
    const int lane = threadIdx.x & 63;
    const int tgt = target[token];
    const int ci = (tgt < 20000) ? 0 : (tgt < 40000) ? 1 : (tgt < 200000) ? 2 : 3;

    {
        const int h = (ci == 0) ? tgt : (20000 + ci - 1);
        const float* row;
        float bb;
        if (h < 20000) { row = W0 + (size_t)h * 1024; bb = b0[h]; }
        else           { row = cw + (size_t)(h - 20000) * 1024; bb = cb[h - 20000]; }
        const unsigned short* y = Y0 + (size_t)token * 1024;
        float s = 0.f;
        for (int k = lane; k < 1024; k += 64) s += bf2f(y[k]) * row[k];
#pragma unroll
        for (int off = 1; off < 64; off <<= 1) s += __shfl_xor(s, off, 64);
        if (lane == 0) headlogit[token] = s + bb;
    }

    float tl = 0.f;
    if (ci > 0) {
        const unsigned short* Y; const float* W; const float* b; int K, ldy, lidx;
        if (ci == 1)      { Y = Y1; W = W1; b = b1; K = 256; ldy = 256; lidx = 20000; }
        else if (ci == 2) { Y = Y2; W = W2; b = b2; K = 64;  ldy = 64;  lidx = 40000; }
        else              { Y = Y3; W = W3; b = b3; K = 16;  ldy = 64;  lidx = 200000; }
        const int r = tgt - lidx;
        const unsigned short* y = Y + (size_t)token * ldy;
        const float* row = W + (size_t)r * K;
        float s = 0.f;
        for (int k = lane; k < K; k += 64) s += bf2f(y[k]) * row[k];
#pragma unroll
        for (int off = 1; off < 64; off <<= 1) s += __shfl_xor(s, off, 64);
        tl = s + b[r];
    }
    if (lane == 0) taillogit[token] = tl;
}

__global__ void finalize_kernel(const float* __restrict__ S,
                                const int* __restrict__ target,
                                const float* __restrict__ headlogit,
                                const float* __restrict__ taillogit,
                                float* __restrict__ out)
{
    __shared__ float red[256];
    const int tid = threadIdx.x;
    float acc = 0.f;
    for (int token = tid; token < 1024; token += 256) {
        const int tgt = target[token];
        const int ci = (tgt < 20000) ? 0 : (tgt < 40000) ? 1 : (tgt < 200000) ? 2 : 3;
        float lp = headlogit[token] - logf(S[token]);
        if (ci > 0)
            lp += taillogit[token] - logf(S[ci * 1024 + token]);
        acc -= lp;
    }
    red[tid] = acc;
    __syncthreads();
    for (int s = 128; s > 0; s >>= 1) {
        if (tid < s) red[tid] += red[tid + s];
        __syncthreads();
    }
    if (tid == 0) out[0] = red[0] * (1.0f / 1024.0f);
}

extern "C" void kernel_launch(void* const* d_in, const int* in_sizes, int n_in,
                              void* d_out, int out_size, void* d_ws, size_t ws_size,
                              hipStream_t stream)
{
    const float* hidden = (const float*)d_in[0];
    const int*   target = (const int*)d_in[1];
    const float* W0 = (const float*)d_in[2];  const float* b0 = (const float*)d_in[3];  const float* P0 = (const float*)d_in[4];
    const float* W1 = (const float*)d_in[5];  const float* b1 = (const float*)d_in[6];  const float* P1 = (const float*)d_in[7];
    const float* W2 = (const float*)d_in[8];  const float* b2 = (const float*)d_in[9];  const float* P2 = (const float*)d_in[10];
    const float* W3 = (const float*)d_in[11]; const float* b3 = (const float*)d_in[12]; const float* P3 = (const float*)d_in[13];
    const float* cw = (const float*)d_in[14]; const float* cb = (const float*)d_in[15];
    float* out = (float*)d_out;

    // ---- workspace layout (byte offsets) ----
    unsigned char* ws = (unsigned char*)d_ws;
    unsigned short* h_bf = (unsigned short*)ws;                       //  2,097,152 B (overlaid later)
    unsigned short* Y0bf = (unsigned short*)(ws + 2097152);           //  2,097,152
    unsigned short* Y1bf = (unsigned short*)(ws + 4194304);           //    524,288
    unsigned short* Y2bf = (unsigned short*)(ws + 4718592);           //    131,072
    unsigned short* Y3bf = (unsigned short*)(ws + 4849664);           //    131,072
    unsigned char* Y0f8 = ws + 4980736;                               //  1,048,576
    unsigned char* Y1f8 = ws + 6029312;                               //    262,144
    unsigned char* Y2f8 = ws + 6291456;                               //     65,536
    unsigned char* Y3f8 = ws + 6356992;                               //     65,536
    unsigned char* Wb0 = ws + 6422528;                                // 20,578,304 (157 tiles)
    unsigned char* Wb1 = ws + 27000832;                               //  5,242,880 (160 tiles)
    unsigned char* Wb2 = ws + 32243712;                               // 10,354,688 (1264 tiles)
    unsigned char* Wb3 = ws + 42598400;                               //  4,456,448 (544 tiles)
    float* bp = (float*)(ws + 47054848);                              //  1,088,000 (272000 f)

    // overlays on h_bf (dead after prepproj)
    float* part0 = (float*)ws;                     // 157*4 KB
    float* part1 = part0 + (size_t)157 * 1024;     //  40*4 KB
    float* part2 = part1 + (size_t)40 * 1024;      //  79*4 KB
    float* part3 = part2 + (size_t)79 * 1024;      //  34*4 KB
    float* S = part3 + (size_t)34 * 1024;          // 4*1024
    float* headlogit = S + 4096;
    float* taillogit = headlogit + 1024;

    cvt_h<<<1024, 256, 0, stream>>>(hidden, h_bf);

    ProjDesc pr0 = { P0, Y0bf, Y0f8, 1024, 1024, 1024, 1024, 0 };
    ProjDesc pr1 = { P1, Y1bf, Y1f8, 256,  256,  256,  256,  8 };
    ProjDesc pr2 = { P2, Y2bf, Y2f8, 64,   64,   64,   64,   10 };
    ProjDesc pr3 = { P3, Y3bf, Y3f8, 64,   16,   16,   64,   11 };
    prepproj<<<2048, 256, 0, stream>>>(h_bf, pr0, pr1, pr2, pr3,
                                       W0, cw, W1, W2, W3,
                                       b0, cb, b1, b2, b3,
                                       Wb0, Wb1, Wb2, Wb3, bp);

    ExpDesc d0 = { Y0f8, Wb0, bp,          part0, 1024, 4, 15, 0,   1 };
    ExpDesc d1 = { Y1f8, Wb1, bp + 20096,  part1, 256,  2, 3,  157, 4 };
    ExpDesc d2 = { Y2f8, Wb2, bp + 40576,  part2, 64,   0, 0,  197, 16 };
    ExpDesc d3 = { Y3f8, Wb3, bp + 202368, part3, 64,   0, 0,  276, 16 };
    exp_gemm<<<dim3(4, 310), 512, 0, stream>>>(d0, d1, d2, d3);

    redext<<<272, 256, 0, stream>>>(part0, part1, part2, part3, S,
                                    Y0bf, Y1bf, Y2bf, Y3bf, target,
                                    W0, b0, W1, b1, W2, b2, W3, b3,
                                    cw, cb, headlogit, taillogit);

    finalize_kernel<<<1, 256, 0, stream>>>(S, target, headlogit, taillogit, out);
}